// Round 5
// baseline (5310.751 us; speedup 1.0000x reference)
//
#include <hip/hip_runtime.h>

typedef _Float16 f16x8 __attribute__((ext_vector_type(8)));
typedef _Float16 f16x4 __attribute__((ext_vector_type(4)));
typedef float f32x4 __attribute__((ext_vector_type(4)));

#define NB 4096  // batch

__device__ __forceinline__ void gload16(const void* g, void* l) {
    __builtin_amdgcn_global_load_lds(
        (const __attribute__((address_space(1))) unsigned int*)g,
        (__attribute__((address_space(3))) unsigned int*)l, 16, 0, 0);
}

// ---------------- transpose + fp16-split of initial x: [4096 f][4096 b] -> Xt[b][f] h/l
__global__ __launch_bounds__(256) void tsplit_kernel(const float* __restrict__ X,
                                                     _Float16* __restrict__ Oh,
                                                     _Float16* __restrict__ Ol) {
    __shared__ float t[64][65];
    const int f0 = blockIdx.x * 64, b0 = blockIdx.y * 64;
    const int tid = threadIdx.x;
    const int jj = tid & 63, i0 = tid >> 6;
#pragma unroll
    for (int p = 0; p < 16; ++p) {
        int i = p * 4 + i0;
        t[i][jj] = X[(size_t)(f0 + i) * NB + b0 + jj];
    }
    __syncthreads();
#pragma unroll
    for (int p = 0; p < 16; ++p) {
        int b = p * 4 + i0;
        float v = t[jj][b];
        size_t idx = (size_t)(b0 + b) * 4096 + f0 + jj;
        _Float16 h = (_Float16)v;
        Oh[idx] = h;
        Ol[idx] = (_Float16)((v - (float)h) * 2048.0f);
    }
}

// ---------------- fp16-split of a weight matrix (elementwise)
__global__ __launch_bounds__(256) void splitw_kernel(const float* __restrict__ W,
                                                     _Float16* __restrict__ Wh,
                                                     _Float16* __restrict__ Wl, long n4) {
    long i = (long)blockIdx.x * 256 + threadIdx.x;
    const long stride = (long)gridDim.x * 256;
    for (; i < n4; i += stride) {
        float4 w = ((const float4*)W)[i];
        float vs[4] = {w.x, w.y, w.z, w.w};
        f16x4 h, l;
#pragma unroll
        for (int j = 0; j < 4; ++j) {
            _Float16 hh = (_Float16)vs[j];
            h[j] = hh;
            l[j] = (_Float16)((vs[j] - (float)hh) * 2048.0f);
        }
        ((f16x4*)Wh)[i] = h;
        ((f16x4*)Wl)[i] = l;
    }
}

// ---------------- pipelined GEMM: C[batch][M] = Xt @ W^T, fp16x2-split 3-MFMA
// Tile 128x128, BK=32, 256 thr = 4 waves (2x2), per-wave 64x64, 1 wave/SIMD
// (512-reg budget). Cross-tile FRAGMENT prefetch: tile t+1's 16 LDS fragment reads
// issue before tile t's 48 MFMAs -> no lgkm waits inside the MFMA phase; LDS port
// and matrix pipe run concurrently. 3x32KB LDS buffers, depth-1 stage batches with
// per-wave vmcnt(0) BEFORE each barrier (publication), T2 XOR swizzle, L3 supertile
// remap. Accumulation order identical to R0 -> bitwise-stable output.
__global__ __launch_bounds__(256, 1) void gemm3p_kernel(
    const _Float16* __restrict__ Ah, const _Float16* __restrict__ Al,
    const _Float16* __restrict__ Bh, const _Float16* __restrict__ Bl,
    float* __restrict__ C, int K, int M, int do_relu) {
    // per buffer 32KB: Ah 8K | Al 8K | Bh 8K | Bl 8K ; x3 = 96KB
    __shared__ __align__(16) char lds[3][32768];

    const int tid = threadIdx.x;
    const int gx = gridDim.x;
    // supertile remap: 256 consecutive hw bids -> SC col-tiles x SR row-tiles block
    int bid = blockIdx.y * gx + blockIdx.x;
    const int SC = gx < 16 ? gx : 16;
    const int SR = 256 / SC;
    const int nsc = gx / SC;
    const int s = bid >> 8, w = bid & 255;
    const int col0 = ((s % nsc) * SC + (w % SC)) * 128;  // feature cols
    const int row0 = ((s / nsc) * SR + (w / SC)) * 128;  // batch rows

    const int wid = tid >> 6, lane = tid & 63;
    const int wm = wid >> 1, wn = wid & 1;  // 2 x 2 waves
    const int lr = lane & 15;
    // read-side swizzle: 16B chunk within a 64B row: chunk' = c ^ ((row>>1)&3)
    const int rdoff = (((lane >> 4) ^ ((lane >> 1) & 3)) << 4);

    f32x4 acc[4][4] = {};
    f32x4 accx[4][4] = {};

    // staging: linear LDS dest (tid*16 within 4KB half-section); inverse-swizzled source
    const int srow = tid >> 2;                     // local row 0..63 (second half +64)
    const int scl = (tid & 3) ^ ((tid >> 3) & 3);  // logical k-chunk for this dest slot
    const size_t sk = (size_t)K;
    const _Float16* gA_h = Ah + (size_t)(row0 + srow) * sk + scl * 8;
    const _Float16* gA_h2 = gA_h + 64 * sk;
    const _Float16* gA_l = Al + (size_t)(row0 + srow) * sk + scl * 8;
    const _Float16* gA_l2 = gA_l + 64 * sk;
    const _Float16* gB_h = Bh + (size_t)(col0 + srow) * sk + scl * 8;
    const _Float16* gB_h2 = gB_h + 64 * sk;
    const _Float16* gB_l = Bl + (size_t)(col0 + srow) * sk + scl * 8;
    const _Float16* gB_l2 = gB_l + 64 * sk;
    const int ldsA = tid * 16;

#define STAGE(Lb, t2)                                         \
    do {                                                      \
        const size_t go = (size_t)(t2) * 32;                  \
        char* L_ = (Lb);                                      \
        gload16(gA_h + go, L_ + ldsA);                        \
        gload16(gA_h2 + go, L_ + 4096 + ldsA);                \
        gload16(gA_l + go, L_ + 8192 + ldsA);                 \
        gload16(gA_l2 + go, L_ + 12288 + ldsA);               \
        gload16(gB_h + go, L_ + 16384 + ldsA);                \
        gload16(gB_h2 + go, L_ + 20480 + ldsA);               \
        gload16(gB_l + go, L_ + 24576 + ldsA);                \
        gload16(gB_l2 + go, L_ + 28672 + ldsA);               \
    } while (0)

#define READF(Lb, ah_, al_, bh_, bl_)                                        \
    do {                                                                     \
        const char* L_ = (Lb);                                               \
        _Pragma("unroll") for (int i = 0; i < 4; ++i) {                      \
            const int ra = wm * 64 + i * 16 + lr;                            \
            const int rb = wn * 64 + i * 16 + lr;                            \
            ah_[i] = *(const f16x8*)(L_ + ra * 64 + rdoff);                  \
            al_[i] = *(const f16x8*)(L_ + 8192 + ra * 64 + rdoff);           \
            bh_[i] = *(const f16x8*)(L_ + 16384 + rb * 64 + rdoff);          \
            bl_[i] = *(const f16x8*)(L_ + 24576 + rb * 64 + rdoff);          \
        }                                                                    \
    } while (0)

#define MFMA16(ah_, al_, bh_, bl_)                                                                       \
    do {                                                                                                 \
        _Pragma("unroll") for (int mi = 0; mi < 4; ++mi) _Pragma("unroll") for (int ni = 0; ni < 4; ++ni) { \
            acc[mi][ni] = __builtin_amdgcn_mfma_f32_16x16x32_f16(ah_[mi], bh_[ni], acc[mi][ni], 0, 0, 0);   \
            accx[mi][ni] = __builtin_amdgcn_mfma_f32_16x16x32_f16(ah_[mi], bl_[ni], accx[mi][ni], 0, 0, 0);  \
            accx[mi][ni] = __builtin_amdgcn_mfma_f32_16x16x32_f16(al_[mi], bh_[ni], accx[mi][ni], 0, 0, 0);  \
        }                                                                                                \
    } while (0)

    f16x8 ahA[4], alA[4], bhA[4], blA[4];
    f16x8 ahB[4], alB[4], bhB[4], blB[4];

    const int NT = K / 32;
    STAGE(lds[0], 0);
    STAGE(lds[1], 1);
    asm volatile("s_waitcnt vmcnt(8)" ::: "memory");  // stage(0) landed, stage(1) in flight
    __builtin_amdgcn_s_barrier();
    READF(lds[0], ahA, alA, bhA, blA);  // tile 0 fragments

    for (int t = 0; t < NT; t += 2) {
        // ---- even: compute tile t (fragA); read tile t+1 -> fragB
        asm volatile("s_waitcnt vmcnt(0)" ::: "memory");  // stage(t+1) landed (this wave)
        __builtin_amdgcn_s_barrier();                     // publish to all waves
        READF(lds[(t + 1) % 3], ahB, alB, bhB, blB);
        if (t + 2 < NT) STAGE(lds[(t + 2) % 3], t + 2);
        __builtin_amdgcn_sched_barrier(0);
        MFMA16(ahA, alA, bhA, blA);
        // ---- odd: compute tile t+1 (fragB); read tile t+2 -> fragA
        if (t + 2 < NT) {
            asm volatile("s_waitcnt vmcnt(0)" ::: "memory");  // stage(t+2) landed
            __builtin_amdgcn_s_barrier();
            READF(lds[(t + 2) % 3], ahA, alA, bhA, blA);
            if (t + 3 < NT) STAGE(lds[(t + 3) % 3], t + 3);
            __builtin_amdgcn_sched_barrier(0);
        }
        MFMA16(ahB, alB, bhB, blB);
    }
#undef STAGE
#undef READF
#undef MFMA16

    // epilogue: combine split accumulators, optional relu, store fp32
#pragma unroll
    for (int mi = 0; mi < 4; ++mi)
#pragma unroll
        for (int ni = 0; ni < 4; ++ni) {
            int colx = col0 + wn * 64 + ni * 16 + lr;
            int rowb = row0 + wm * 64 + mi * 16 + ((lane >> 4) << 2);
#pragma unroll
            for (int r = 0; r < 4; ++r) {
                float v = acc[mi][ni][r] + accx[mi][ni][r] * (1.0f / 2048.0f);
                if (do_relu) v = fmaxf(v, 0.0f);
                C[(size_t)(rowb + r) * M + colx] = v;
            }
        }
}

// ---------------- kWTA: exact k-th largest of (x - thr[col]) per row via 4x8-bit radix
template <int CNT, bool SOFTMAX>
__global__ __launch_bounds__(256) void kwta_kernel(const float* __restrict__ Cin,
                                                   const float* __restrict__ thr,
                                                   _Float16* __restrict__ Oh,
                                                   _Float16* __restrict__ Ol,
                                                   float* __restrict__ outT, int M, int k) {
    const int row = blockIdx.x, tid = threadIdx.x;
    const float* rp = Cin + (size_t)row * M;
    unsigned uv[CNT];
    float xv[CNT];
#pragma unroll
    for (int i = 0; i < CNT; ++i) {
        int col = i * 256 + tid;
        float x = rp[col];
        float a = x - thr[col];
        unsigned b = __float_as_uint(a);
        uv[i] = (b & 0x80000000u) ? ~b : (b | 0x80000000u);
        xv[i] = x;
    }
    __shared__ int hist[256];
    __shared__ unsigned sel_s;
    __shared__ int kk_s;
    unsigned prefix = 0;
    int kk = k;
#pragma unroll
    for (int pass = 0; pass < 4; ++pass) {
        const int shift = 24 - pass * 8;
        hist[tid] = 0;
        __syncthreads();
#pragma unroll
        for (int i = 0; i < CNT; ++i) {
            bool ok = (pass == 0) || ((uv[i] >> (shift + 8)) == prefix);
            if (ok) atomicAdd(&hist[(uv[i] >> shift) & 255], 1);
        }
        __syncthreads();
        for (int off = 1; off < 256; off <<= 1) {
            int v = hist[tid] + ((tid + off < 256) ? hist[tid + off] : 0);
            __syncthreads();
            hist[tid] = v;
            __syncthreads();
        }
        if (hist[tid] >= kk && (tid == 255 || hist[tid + 1] < kk)) {
            sel_s = (unsigned)tid;
            kk_s = kk - ((tid == 255) ? 0 : hist[tid + 1]);
        }
        __syncthreads();
        prefix = (prefix << 8) | sel_s;
        kk = kk_s;
        __syncthreads();
    }
    const unsigned kth = prefix;
    if (!SOFTMAX) {
#pragma unroll
        for (int i = 0; i < CNT; ++i) {
            int col = i * 256 + tid;
            float v = (uv[i] >= kth) ? xv[i] : 0.0f;
            size_t idx = (size_t)row * M + col;
            _Float16 h = (_Float16)v;
            Oh[idx] = h;
            Ol[idx] = (_Float16)((v - (float)h) * 2048.0f);
        }
    } else {
        float vals[CNT];
        float m = -3.4e38f;
#pragma unroll
        for (int i = 0; i < CNT; ++i) {
            float v = (uv[i] >= kth) ? xv[i] : 0.0f;
            vals[i] = v;
            m = fmaxf(m, v);
        }
        for (int off = 32; off; off >>= 1) m = fmaxf(m, __shfl_xor(m, off));
        __shared__ float redm[4];
        if ((tid & 63) == 0) redm[tid >> 6] = m;
        __syncthreads();
        m = fmaxf(fmaxf(redm[0], redm[1]), fmaxf(redm[2], redm[3]));
        float s = 0.0f, e[CNT];
#pragma unroll
        for (int i = 0; i < CNT; ++i) {
            e[i] = expf(vals[i] - m);
            s += e[i];
        }
        for (int off = 32; off; off >>= 1) s += __shfl_xor(s, off);
        __shared__ float reds[4];
        if ((tid & 63) == 0) reds[tid >> 6] = s;
        __syncthreads();
        s = reds[0] + reds[1] + reds[2] + reds[3];
        float inv = 1.0f / s;
#pragma unroll
        for (int i = 0; i < CNT; ++i)
            outT[(size_t)(i * 256 + tid) * NB + row] = e[i] * inv;
    }
}

extern "C" void kernel_launch(void* const* d_in, const int* in_sizes, int n_in,
                              void* d_out, int out_size, void* d_ws, size_t ws_size,
                              hipStream_t stream) {
    const float* x = (const float*)d_in[0];
    const float* W0 = (const float*)d_in[1];
    const float* thr0 = (const float*)d_in[2];
    const float* W1 = (const float*)d_in[3];
    const float* thr1 = (const float*)d_in[4];
    const float* W2 = (const float*)d_in[5];
    const float* thr2 = (const float*)d_in[6];
    const float* W3 = (const float*)d_in[7];
    const float* thr3 = (const float*)d_in[8];
    float* out = (float*)d_out;

    char* ws = (char*)d_ws;
    size_t off = 0;
    auto alloc = [&](size_t bytes) {
        void* p = ws + off;
        off += (bytes + 255) & ~(size_t)255;
        return p;
    };
    _Float16* Wh = (_Float16*)alloc((size_t)8192 * 8192 * 2);
    _Float16* Wl = (_Float16*)alloc((size_t)8192 * 8192 * 2);
    _Float16* Xh = (_Float16*)alloc((size_t)4096 * 8192 * 2);
    _Float16* Xl = (_Float16*)alloc((size_t)4096 * 8192 * 2);
    _Float16* Yh = (_Float16*)alloc((size_t)4096 * 8192 * 2);
    _Float16* Yl = (_Float16*)alloc((size_t)4096 * 8192 * 2);
    float* C32 = (float*)alloc((size_t)4096 * 8192 * 4);

    tsplit_kernel<<<dim3(64, 64), 256, 0, stream>>>(x, Xh, Xl);

    // layer 0: K=4096, M=8192, relu, k=409
    splitw_kernel<<<4096, 256, 0, stream>>>(W0, Wh, Wl, (long)8192 * 4096 / 4);
    gemm3p_kernel<<<dim3(8192 / 128, NB / 128), 256, 0, stream>>>(Xh, Xl, Wh, Wl, C32, 4096, 8192, 1);
    kwta_kernel<32, false><<<NB, 256, 0, stream>>>(C32, thr0, Yh, Yl, nullptr, 8192, 409);

    // layer 1: K=8192, M=8192, relu, k=409
    splitw_kernel<<<4096, 256, 0, stream>>>(W1, Wh, Wl, (long)8192 * 8192 / 4);
    gemm3p_kernel<<<dim3(8192 / 128, NB / 128), 256, 0, stream>>>(Yh, Yl, Wh, Wl, C32, 8192, 8192, 1);
    kwta_kernel<32, false><<<NB, 256, 0, stream>>>(C32, thr1, Xh, Xl, nullptr, 8192, 409);

    // layer 2: K=8192, M=4096, relu, k=204
    splitw_kernel<<<4096, 256, 0, stream>>>(W2, Wh, Wl, (long)4096 * 8192 / 4);
    gemm3p_kernel<<<dim3(4096 / 128, NB / 128), 256, 0, stream>>>(Xh, Xl, Wh, Wl, C32, 8192, 4096, 1);
    kwta_kernel<16, false><<<NB, 256, 0, stream>>>(C32, thr2, Yh, Yl, nullptr, 4096, 204);

    // layer 3: K=4096, M=1024, no relu, k=51, then softmax -> out [1024][4096]
    splitw_kernel<<<4096, 256, 0, stream>>>(W3, Wh, Wl, (long)1024 * 4096 / 4);
    gemm3p_kernel<<<dim3(1024 / 128, NB / 128), 256, 0, stream>>>(Yh, Yl, Wh, Wl, C32, 4096, 1024, 0);
    kwta_kernel<4, true><<<NB, 256, 0, stream>>>(C32, thr3, nullptr, nullptr, out, 1024, 51);
}

// Round 6
// 3362.264 us; speedup vs baseline: 1.5795x; 1.5795x over previous
//
#include <hip/hip_runtime.h>

typedef _Float16 f16x8 __attribute__((ext_vector_type(8)));
typedef _Float16 f16x4 __attribute__((ext_vector_type(4)));
typedef float f32x4 __attribute__((ext_vector_type(4)));

#define NB 4096  // batch

__device__ __forceinline__ void gload16(const void* g, void* l) {
    __builtin_amdgcn_global_load_lds(
        (const __attribute__((address_space(1))) unsigned int*)g,
        (__attribute__((address_space(3))) unsigned int*)l, 16, 0, 0);
}

// ---------------- transpose + fp16-split of initial x: [4096 f][4096 b] -> Xt[b][f] h/l
__global__ __launch_bounds__(256) void tsplit_kernel(const float* __restrict__ X,
                                                     _Float16* __restrict__ Oh,
                                                     _Float16* __restrict__ Ol) {
    __shared__ float t[64][65];
    const int f0 = blockIdx.x * 64, b0 = blockIdx.y * 64;
    const int tid = threadIdx.x;
    const int jj = tid & 63, i0 = tid >> 6;
#pragma unroll
    for (int p = 0; p < 16; ++p) {
        int i = p * 4 + i0;
        t[i][jj] = X[(size_t)(f0 + i) * NB + b0 + jj];
    }
    __syncthreads();
#pragma unroll
    for (int p = 0; p < 16; ++p) {
        int b = p * 4 + i0;
        float v = t[jj][b];
        size_t idx = (size_t)(b0 + b) * 4096 + f0 + jj;
        _Float16 h = (_Float16)v;
        Oh[idx] = h;
        Ol[idx] = (_Float16)((v - (float)h) * 2048.0f);
    }
}

// ---------------- fp16-split of a weight matrix (elementwise)
__global__ __launch_bounds__(256) void splitw_kernel(const float* __restrict__ W,
                                                     _Float16* __restrict__ Wh,
                                                     _Float16* __restrict__ Wl, long n4) {
    long i = (long)blockIdx.x * 256 + threadIdx.x;
    const long stride = (long)gridDim.x * 256;
    for (; i < n4; i += stride) {
        float4 w = ((const float4*)W)[i];
        float vs[4] = {w.x, w.y, w.z, w.w};
        f16x4 h, l;
#pragma unroll
        for (int j = 0; j < 4; ++j) {
            _Float16 hh = (_Float16)vs[j];
            h[j] = hh;
            l[j] = (_Float16)((vs[j] - (float)hh) * 2048.0f);
        }
        ((f16x4*)Wh)[i] = h;
        ((f16x4*)Wl)[i] = l;
    }
}

// ---------------- pipelined GEMM: C[batch][M] = Xt @ W^T, fp16x2-split 3-MFMA
// Tile 128x128, BK=32, 256 thr = 4 waves (2x2), per-wave 64x64, single-buffered frags
// (~230 unified regs -> 2 waves/SIMD). LDS 2 x 32KB = 64KB -> 2 BLOCKS/CU: independent
// barrier domains so one block's MFMA phase covers the other's read/stage phase.
// Depth-1 staging with vmcnt(0)-at-top (waits only this wave's 8 loads), R3-style
// diagonal lgkm-counted read/MFMA interleave + staggered staging + T2 swizzle +
// 512-block supertile window (A 134MB + B 67MB < 256MB L3).
__global__ __launch_bounds__(256, 2) void gemm3p_kernel(
    const _Float16* __restrict__ Ah, const _Float16* __restrict__ Al,
    const _Float16* __restrict__ Bh, const _Float16* __restrict__ Bl,
    float* __restrict__ C, int K, int M, int do_relu) {
    // per buffer 32KB: Ah 8K | Al 8K | Bh 8K | Bl 8K ; x2 = 64KB
    __shared__ __align__(16) char lds[2][32768];

    const int tid = threadIdx.x;
    const int gx = gridDim.x, gy = gridDim.y;
    // supertile remap: 512 consecutive hw bids -> SC col-tiles x SR row-tiles window
    int bid = blockIdx.y * gx + blockIdx.x;
    const int SC = gx < 16 ? gx : 16;
    int SR = 512 / SC; if (SR > gy) SR = gy;
    const int W = SC * SR;
    const int nsc = gx / SC;
    const int s = bid / W, w = bid % W;
    const int col0 = ((s % nsc) * SC + (w % SC)) * 128;  // feature cols
    const int row0 = ((s / nsc) * SR + (w / SC)) * 128;  // batch rows

    const int wid = tid >> 6, lane = tid & 63;
    const int wm = wid >> 1, wn = wid & 1;  // 2 x 2 waves
    const int lr = lane & 15;
    // read-side swizzle: 16B chunk within a 64B row: chunk' = c ^ ((row>>1)&3)
    const int rdoff = (((lane >> 4) ^ ((lane >> 1) & 3)) << 4);

    f32x4 acc[4][4] = {};
    f32x4 accx[4][4] = {};

    // staging: linear LDS dest (tid*16 per 4KB half-section); inverse-swizzled source
    const int srow = tid >> 2;                     // local row 0..63 (half2 = +64)
    const int scl = (tid & 3) ^ ((tid >> 3) & 3);  // logical k-chunk for this dest slot
    const size_t sk = (size_t)K;
    const _Float16* gA_h = Ah + (size_t)(row0 + srow) * sk + scl * 8;
    const _Float16* gA_h2 = gA_h + 64 * sk;
    const _Float16* gA_l = Al + (size_t)(row0 + srow) * sk + scl * 8;
    const _Float16* gA_l2 = gA_l + 64 * sk;
    const _Float16* gB_h = Bh + (size_t)(col0 + srow) * sk + scl * 8;
    const _Float16* gB_h2 = gB_h + 64 * sk;
    const _Float16* gB_l = Bl + (size_t)(col0 + srow) * sk + scl * 8;
    const _Float16* gB_l2 = gB_l + 64 * sk;
    const int ldsA = tid * 16;

#define SA0(Lb, go) { gload16(gA_h + go, (Lb) + ldsA); gload16(gA_h2 + go, (Lb) + 4096 + ldsA); }
#define SA1(Lb, go) { gload16(gA_l + go, (Lb) + 8192 + ldsA); gload16(gA_l2 + go, (Lb) + 12288 + ldsA); }
#define SB0(Lb, go) { gload16(gB_h + go, (Lb) + 16384 + ldsA); gload16(gB_h2 + go, (Lb) + 20480 + ldsA); }
#define SB1(Lb, go) { gload16(gB_l + go, (Lb) + 24576 + ldsA); gload16(gB_l2 + go, (Lb) + 28672 + ldsA); }

    const int NT = K / 32;
    {  // prologue: tile 0 into buffer 0
        SA0(lds[0], 0) SA1(lds[0], 0) SB0(lds[0], 0) SB1(lds[0], 0)
    }

    for (int t = 0; t < NT; ++t) {
        asm volatile("s_waitcnt vmcnt(0)" ::: "memory");  // stage(t) landed (this wave)
        __builtin_amdgcn_s_barrier();                     // publish; prior reads done
        asm volatile("" ::: "memory");

        const char* Lb = lds[t & 1];
        char* Ls = lds[(t + 1) & 1];  // stage dest (tile t-1's reads completed)
        const bool do_stage = (t + 1 < NT);
        const size_t go = (size_t)(t + 1) * 32;

        f16x8 ah[4], al[4], bh[4], bl[4];
#define READG(i)                                                              \
    {                                                                         \
        const int ra = wm * 64 + (i)*16 + lr;                                 \
        const int rb = wn * 64 + (i)*16 + lr;                                 \
        ah[i] = *(const f16x8*)(Lb + ra * 64 + rdoff);                        \
        al[i] = *(const f16x8*)(Lb + 8192 + ra * 64 + rdoff);                 \
        bh[i] = *(const f16x8*)(Lb + 16384 + rb * 64 + rdoff);                \
        bl[i] = *(const f16x8*)(Lb + 24576 + rb * 64 + rdoff);                \
    }
#define CL(mi, ni)                                                                               \
    {                                                                                            \
        acc[mi][ni] = __builtin_amdgcn_mfma_f32_16x16x32_f16(ah[mi], bh[ni], acc[mi][ni], 0, 0, 0);  \
        accx[mi][ni] = __builtin_amdgcn_mfma_f32_16x16x32_f16(ah[mi], bl[ni], accx[mi][ni], 0, 0, 0); \
        accx[mi][ni] = __builtin_amdgcn_mfma_f32_16x16x32_f16(al[mi], bh[ni], accx[mi][ni], 0, 0, 0); \
    }
        READG(0)
        READG(1)
        if (do_stage) SA0(Ls, go)
        asm volatile("s_waitcnt lgkmcnt(4)" ::: "memory");  // G0 ready, G1 in flight
        __builtin_amdgcn_sched_barrier(0);
        __builtin_amdgcn_s_setprio(1);
        CL(0, 0)
        __builtin_amdgcn_s_setprio(0);

        READG(2)
        if (do_stage) SA1(Ls, go)
        asm volatile("s_waitcnt lgkmcnt(4)" ::: "memory");  // G1 ready, G2 in flight
        __builtin_amdgcn_sched_barrier(0);
        __builtin_amdgcn_s_setprio(1);
        CL(0, 1) CL(1, 0) CL(1, 1)
        __builtin_amdgcn_s_setprio(0);

        READG(3)
        if (do_stage) SB0(Ls, go)
        asm volatile("s_waitcnt lgkmcnt(4)" ::: "memory");  // G2 ready, G3 in flight
        __builtin_amdgcn_sched_barrier(0);
        __builtin_amdgcn_s_setprio(1);
        CL(0, 2) CL(1, 2) CL(2, 0) CL(2, 1) CL(2, 2)
        __builtin_amdgcn_s_setprio(0);

        if (do_stage) SB1(Ls, go)
        asm volatile("s_waitcnt lgkmcnt(0)" ::: "memory");  // G3 ready
        __builtin_amdgcn_sched_barrier(0);
        __builtin_amdgcn_s_setprio(1);
        CL(0, 3) CL(1, 3) CL(2, 3) CL(3, 0) CL(3, 1) CL(3, 2) CL(3, 3)
        __builtin_amdgcn_s_setprio(0);
#undef READG
#undef CL
    }
#undef SA0
#undef SA1
#undef SB0
#undef SB1

    // epilogue: combine split accumulators, optional relu, store fp32
#pragma unroll
    for (int mi = 0; mi < 4; ++mi)
#pragma unroll
        for (int ni = 0; ni < 4; ++ni) {
            int colx = col0 + wn * 64 + ni * 16 + lr;
            int rowb = row0 + wm * 64 + mi * 16 + ((lane >> 4) << 2);
#pragma unroll
            for (int r = 0; r < 4; ++r) {
                float v = acc[mi][ni][r] + accx[mi][ni][r] * (1.0f / 2048.0f);
                if (do_relu) v = fmaxf(v, 0.0f);
                C[(size_t)(rowb + r) * M + colx] = v;
            }
        }
}

// ---------------- kWTA: exact k-th largest of (x - thr[col]) per row via 4x8-bit radix
template <int CNT, bool SOFTMAX>
__global__ __launch_bounds__(256) void kwta_kernel(const float* __restrict__ Cin,
                                                   const float* __restrict__ thr,
                                                   _Float16* __restrict__ Oh,
                                                   _Float16* __restrict__ Ol,
                                                   float* __restrict__ outT, int M, int k) {
    const int row = blockIdx.x, tid = threadIdx.x;
    const float* rp = Cin + (size_t)row * M;
    unsigned uv[CNT];
    float xv[CNT];
#pragma unroll
    for (int i = 0; i < CNT; ++i) {
        int col = i * 256 + tid;
        float x = rp[col];
        float a = x - thr[col];
        unsigned b = __float_as_uint(a);
        uv[i] = (b & 0x80000000u) ? ~b : (b | 0x80000000u);
        xv[i] = x;
    }
    __shared__ int hist[256];
    __shared__ unsigned sel_s;
    __shared__ int kk_s;
    unsigned prefix = 0;
    int kk = k;
#pragma unroll
    for (int pass = 0; pass < 4; ++pass) {
        const int shift = 24 - pass * 8;
        hist[tid] = 0;
        __syncthreads();
#pragma unroll
        for (int i = 0; i < CNT; ++i) {
            bool ok = (pass == 0) || ((uv[i] >> (shift + 8)) == prefix);
            if (ok) atomicAdd(&hist[(uv[i] >> shift) & 255], 1);
        }
        __syncthreads();
        for (int off = 1; off < 256; off <<= 1) {
            int v = hist[tid] + ((tid + off < 256) ? hist[tid + off] : 0);
            __syncthreads();
            hist[tid] = v;
            __syncthreads();
        }
        if (hist[tid] >= kk && (tid == 255 || hist[tid + 1] < kk)) {
            sel_s = (unsigned)tid;
            kk_s = kk - ((tid == 255) ? 0 : hist[tid + 1]);
        }
        __syncthreads();
        prefix = (prefix << 8) | sel_s;
        kk = kk_s;
        __syncthreads();
    }
    const unsigned kth = prefix;
    if (!SOFTMAX) {
#pragma unroll
        for (int i = 0; i < CNT; ++i) {
            int col = i * 256 + tid;
            float v = (uv[i] >= kth) ? xv[i] : 0.0f;
            size_t idx = (size_t)row * M + col;
            _Float16 h = (_Float16)v;
            Oh[idx] = h;
            Ol[idx] = (_Float16)((v - (float)h) * 2048.0f);
        }
    } else {
        float vals[CNT];
        float m = -3.4e38f;
#pragma unroll
        for (int i = 0; i < CNT; ++i) {
            float v = (uv[i] >= kth) ? xv[i] : 0.0f;
            vals[i] = v;
            m = fmaxf(m, v);
        }
        for (int off = 32; off; off >>= 1) m = fmaxf(m, __shfl_xor(m, off));
        __shared__ float redm[4];
        if ((tid & 63) == 0) redm[tid >> 6] = m;
        __syncthreads();
        m = fmaxf(fmaxf(redm[0], redm[1]), fmaxf(redm[2], redm[3]));
        float s = 0.0f, e[CNT];
#pragma unroll
        for (int i = 0; i < CNT; ++i) {
            e[i] = expf(vals[i] - m);
            s += e[i];
        }
        for (int off = 32; off; off >>= 1) s += __shfl_xor(s, off);
        __shared__ float reds[4];
        if ((tid & 63) == 0) reds[tid >> 6] = s;
        __syncthreads();
        s = reds[0] + reds[1] + reds[2] + reds[3];
        float inv = 1.0f / s;
#pragma unroll
        for (int i = 0; i < CNT; ++i)
            outT[(size_t)(i * 256 + tid) * NB + row] = e[i] * inv;
    }
}

extern "C" void kernel_launch(void* const* d_in, const int* in_sizes, int n_in,
                              void* d_out, int out_size, void* d_ws, size_t ws_size,
                              hipStream_t stream) {
    const float* x = (const float*)d_in[0];
    const float* W0 = (const float*)d_in[1];
    const float* thr0 = (const float*)d_in[2];
    const float* W1 = (const float*)d_in[3];
    const float* thr1 = (const float*)d_in[4];
    const float* W2 = (const float*)d_in[5];
    const float* thr2 = (const float*)d_in[6];
    const float* W3 = (const float*)d_in[7];
    const float* thr3 = (const float*)d_in[8];
    float* out = (float*)d_out;

    char* ws = (char*)d_ws;
    size_t off = 0;
    auto alloc = [&](size_t bytes) {
        void* p = ws + off;
        off += (bytes + 255) & ~(size_t)255;
        return p;
    };
    _Float16* Wh = (_Float16*)alloc((size_t)8192 * 8192 * 2);
    _Float16* Wl = (_Float16*)alloc((size_t)8192 * 8192 * 2);
    _Float16* Xh = (_Float16*)alloc((size_t)4096 * 8192 * 2);
    _Float16* Xl = (_Float16*)alloc((size_t)4096 * 8192 * 2);
    _Float16* Yh = (_Float16*)alloc((size_t)4096 * 8192 * 2);
    _Float16* Yl = (_Float16*)alloc((size_t)4096 * 8192 * 2);
    float* C32 = (float*)alloc((size_t)4096 * 8192 * 4);

    tsplit_kernel<<<dim3(64, 64), 256, 0, stream>>>(x, Xh, Xl);

    // layer 0: K=4096, M=8192, relu, k=409
    splitw_kernel<<<4096, 256, 0, stream>>>(W0, Wh, Wl, (long)8192 * 4096 / 4);
    gemm3p_kernel<<<dim3(8192 / 128, NB / 128), 256, 0, stream>>>(Xh, Xl, Wh, Wl, C32, 4096, 8192, 1);
    kwta_kernel<32, false><<<NB, 256, 0, stream>>>(C32, thr0, Yh, Yl, nullptr, 8192, 409);

    // layer 1: K=8192, M=8192, relu, k=409
    splitw_kernel<<<4096, 256, 0, stream>>>(W1, Wh, Wl, (long)8192 * 8192 / 4);
    gemm3p_kernel<<<dim3(8192 / 128, NB / 128), 256, 0, stream>>>(Yh, Yl, Wh, Wl, C32, 8192, 8192, 1);
    kwta_kernel<32, false><<<NB, 256, 0, stream>>>(C32, thr1, Xh, Xl, nullptr, 8192, 409);

    // layer 2: K=8192, M=4096, relu, k=204
    splitw_kernel<<<4096, 256, 0, stream>>>(W2, Wh, Wl, (long)4096 * 8192 / 4);
    gemm3p_kernel<<<dim3(4096 / 128, NB / 128), 256, 0, stream>>>(Xh, Xl, Wh, Wl, C32, 8192, 4096, 1);
    kwta_kernel<16, false><<<NB, 256, 0, stream>>>(C32, thr2, Yh, Yl, nullptr, 4096, 204);

    // layer 3: K=4096, M=1024, no relu, k=51, then softmax -> out [1024][4096]
    splitw_kernel<<<4096, 256, 0, stream>>>(W3, Wh, Wl, (long)1024 * 4096 / 4);
    gemm3p_kernel<<<dim3(1024 / 128, NB / 128), 256, 0, stream>>>(Yh, Yl, Wh, Wl, C32, 4096, 1024, 0);
    kwta_kernel<4, true><<<NB, 256, 0, stream>>>(C32, thr3, nullptr, nullptr, out, 1024, 51);
}